// Round 5
// baseline (296.248 us; speedup 1.0000x reference)
//
#include <hip/hip_runtime.h>

// 14-qubit state-vector sim, one workgroup per batch element, state in LDS.
// Wire w <-> bit (13-w). CNOT rings folded into scatter writes.
// R11: R10 (1024 thr x 16 amps, 4 register-butterfly passes/layer, verified
//      correct) with two perf fixes:
//      (a) XOR-swizzle LDS layout slot(i) = i ^ ((i>>6)&15) instead of
//          additive padding — makes every pass's b64 access optimally
//          bank-spread (R10's LO=2 pass was 4-way, ring pass 8-way).
//      (b) __launch_bounds__(1024) without the waves/EU arg — R10's
//          VGPR_Count=64 + 60 MB/dispatch HBM traffic = allocator picked
//          64 regs and spilled; let it take ~90-128 (LDS caps occupancy
//          at 16 waves/CU regardless).

#define NW 14
#define NSTATE (1 << NW)                      // 16384
#define NTHREADS 1024
#define STATE_SLOTS NSTATE                    // exact: swizzle, no pads

typedef float v2f __attribute__((ext_vector_type(2)));

// ---- VOP3P packed helpers (verified R5 semantics) ----
__device__ __forceinline__ v2f pk_mul_bl(v2f a, v2f b) {   // {a.lo*b.lo, a.hi*b.lo}
    v2f d; asm("v_pk_mul_f32 %0, %1, %2 op_sel:[0,0] op_sel_hi:[1,0]"
               : "=v"(d) : "v"(a), "v"(b)); return d;
}
__device__ __forceinline__ v2f pk_fma_bl(v2f a, v2f b, v2f c) {
    v2f d; asm("v_pk_fma_f32 %0, %1, %2, %3 op_sel:[0,0,0] op_sel_hi:[1,0,1]"
               : "=v"(d) : "v"(a), "v"(b), "v"(c)); return d;
}
__device__ __forceinline__ v2f pk_fma_sw(v2f a, v2f b, v2f c) { // {a.hi*b.lo+c.lo, a.lo*b.hi+c.hi}
    v2f d; asm("v_pk_fma_f32 %0, %1, %2, %3 op_sel:[1,0,0] op_sel_hi:[0,1,1]"
               : "=v"(d) : "v"(a), "v"(b), "v"(c)); return d;
}

// ---- compile-time CNOT-ring constants ----
struct RingConsts {
    unsigned col[2][NW];      // image of basis bit under ring map (ri=0: r=1, ri=1: r=2)
    unsigned flow4[2][16];    // image of amp sub-index k (i bits 3..0)
};
constexpr RingConsts make_rc() {
    RingConsts rc{};
    for (int ri = 0; ri < 2; ++ri) {
        for (int bb = 0; bb < NW; ++bb) {
            unsigned x = 1u << bb;
            for (int w = 0; w < NW; ++w) {
                int pc = 13 - w, pt = 13 - ((w + ri + 1) % NW);
                x ^= ((x >> pc) & 1u) << pt;
            }
            rc.col[ri][bb] = x;
        }
        for (int k = 0; k < 16; ++k) {
            unsigned x = 0;
            for (int b = 0; b < 4; ++b) if ((k >> b) & 1) x ^= rc.col[ri][b];
            rc.flow4[ri][k] = x;
        }
    }
    return rc;
}
constexpr RingConsts RC = make_rc();

// base image for i = t<<4 (t bit b -> i bit b+4)
template<int RI>
__device__ __forceinline__ unsigned fbase(int t) {
    unsigned x = 0;
#pragma unroll
    for (int b = 0; b < 10; ++b) if ((t >> b) & 1) x ^= RC.col[RI][b + 4];
    return x;
}

// Gate consts per wire W (4 float4 per gate: {u.re, u.im, -u.im, +u.im})
#define GSTAGE(W) \
    const float4 g0 = G4[(W)*4+0], g1 = G4[(W)*4+1], \
                 g2 = G4[(W)*4+2], g3 = G4[(W)*4+3]; \
    const v2f U00 = (v2f){g0.x,g0.y}, V00 = (v2f){g0.z,g0.w}; \
    const v2f U01 = (v2f){g1.x,g1.y}, V01 = (v2f){g1.z,g1.w}; \
    const v2f U10 = (v2f){g2.x,g2.y}, V10 = (v2f){g2.z,g2.w}; \
    const v2f U11 = (v2f){g3.x,g3.y}, V11 = (v2f){g3.z,g3.w};

#define CBFA(X, Y) { \
    v2f n0 = pk_mul_bl(X, U00); n0 = pk_fma_sw(X, V00, n0); \
    n0 = pk_fma_bl(Y, U01, n0); n0 = pk_fma_sw(Y, V01, n0); \
    v2f n1 = pk_mul_bl(X, U10); n1 = pk_fma_sw(X, V10, n1); \
    n1 = pk_fma_bl(Y, U11, n1); n1 = pk_fma_sw(Y, V11, n1); \
    X = n0; Y = n1; }

#define FE16(M) M(0) M(1) M(2) M(3) M(4) M(5) M(6) M(7) \
                M(8) M(9) M(10) M(11) M(12) M(13) M(14) M(15)

// butterfly pair lists per k-bit (first arg has k-bit = 0)
#define Q3(M) M(A0,A8) M(A1,A9) M(A2,A10) M(A3,A11) M(A4,A12) M(A5,A13) M(A6,A14) M(A7,A15)
#define Q2(M) M(A0,A4) M(A1,A5) M(A2,A6) M(A3,A7) M(A8,A12) M(A9,A13) M(A10,A14) M(A11,A15)
#define Q1(M) M(A0,A2) M(A1,A3) M(A4,A6) M(A5,A7) M(A8,A10) M(A9,A11) M(A12,A14) M(A13,A15)
#define Q0(M) M(A0,A1) M(A2,A3) M(A4,A5) M(A6,A7) M(A8,A9) M(A10,A11) M(A12,A13) M(A14,A15)

// ---- pass HI: i = (k<<10)|t ; slot = i ^ ((t>>6)&15). wires 0..3 on k bits ----
__device__ __forceinline__ void pass_hi(float2* st_, const float4* G4, int t)
{
    float2* p = st_ + (t ^ ((t >> 6) & 15));
#define LDH(k) v2f A##k = *(const v2f*)(p + ((k) << 10));
    FE16(LDH)
#undef LDH
    { GSTAGE(0) Q3(CBFA) }      // wire 0 <-> i bit 13
    { GSTAGE(1) Q2(CBFA) }      // wire 1 <-> i bit 12
    { GSTAGE(2) Q1(CBFA) }      // wire 2 <-> i bit 11
    { GSTAGE(3) Q0(CBFA) }      // wire 3 <-> i bit 10
#define STH(k) *(v2f*)(p + ((k) << 10)) = A##k;
    FE16(STH)
#undef STH
}

// ---- pass MID: i = ((t>>6)<<10)|(k<<6)|(t&63); slot = i ^ k. wires 4..7 ----
__device__ __forceinline__ void pass_mid(float2* st_, const float4* G4, int t)
{
    const int L = t & 63;
    float2* p = st_ + ((t >> 6) << 10);
#define LDM(k) v2f A##k = *(const v2f*)(p + (((k) << 6) | (L ^ (k))));
    FE16(LDM)
#undef LDM
    { GSTAGE(4) Q3(CBFA) }      // wire 4 <-> i bit 9
    { GSTAGE(5) Q2(CBFA) }      // wire 5 <-> i bit 8
    { GSTAGE(6) Q1(CBFA) }      // wire 6 <-> i bit 7
    { GSTAGE(7) Q0(CBFA) }      // wire 7 <-> i bit 6
#define STM(k) *(v2f*)(p + (((k) << 6) | (L ^ (k)))) = A##k;
    FE16(STM)
#undef STM
}

// ---- pass LO2: i = ((t>>2)<<6)|(k<<2)|(t&3); slot = i ^ c, c=(t>>2)&15. wires 8..11 ----
__device__ __forceinline__ void pass_lo2(float2* st_, const float4* G4, int t)
{
    const int c  = (t >> 2) & 15;
    const int ck = c >> 2;                       // XOR on k bits [1:0]
    float2* p = st_ + (((t >> 2) << 6) | ((t & 3) ^ (c & 3)));
#define LDL(k) v2f A##k = *(const v2f*)(p + (((k) ^ ck) << 2));
    FE16(LDL)
#undef LDL
    { GSTAGE(8)  Q3(CBFA) }     // wire 8  <-> i bit 5
    { GSTAGE(9)  Q2(CBFA) }     // wire 9  <-> i bit 4
    { GSTAGE(10) Q1(CBFA) }     // wire 10 <-> i bit 3
    { GSTAGE(11) Q0(CBFA) }     // wire 11 <-> i bit 2
#define STL(k) *(v2f*)(p + (((k) ^ ck) << 2)) = A##k;
    FE16(STL)
#undef STL
}

// ---- final pass of a layer: i = (t<<4)|k; slot = i ^ c. wires 12,13 + ring scatter ----
#define RING_LOAD_GATES \
    const int c = (t >> 2) & 15; \
    float2* p = st_ + (t << 4); \
    v2f A0  = *(const v2f*)(p + ( 0 ^ c)), A1  = *(const v2f*)(p + ( 1 ^ c)), \
        A2  = *(const v2f*)(p + ( 2 ^ c)), A3  = *(const v2f*)(p + ( 3 ^ c)), \
        A4  = *(const v2f*)(p + ( 4 ^ c)), A5  = *(const v2f*)(p + ( 5 ^ c)), \
        A6  = *(const v2f*)(p + ( 6 ^ c)), A7  = *(const v2f*)(p + ( 7 ^ c)), \
        A8  = *(const v2f*)(p + ( 8 ^ c)), A9  = *(const v2f*)(p + ( 9 ^ c)), \
        A10 = *(const v2f*)(p + (10 ^ c)), A11 = *(const v2f*)(p + (11 ^ c)), \
        A12 = *(const v2f*)(p + (12 ^ c)), A13 = *(const v2f*)(p + (13 ^ c)), \
        A14 = *(const v2f*)(p + (14 ^ c)), A15 = *(const v2f*)(p + (15 ^ c)); \
    { GSTAGE(12) Q1(CBFA) }        /* wire 12 <-> i bit 1 */ \
    { GSTAGE(13) Q0(CBFA) }        /* wire 13 <-> i bit 0 */

template<int RI>
__device__ __forceinline__ void ring_pass(float2* st_, const float4* G4, int t,
                                          unsigned fb)
{
    RING_LOAD_GATES
    __syncthreads();                             // all reads done before scatter
#define SC(k) { unsigned ix = fb ^ RC.flow4[RI][(k)]; \
    ix ^= (ix >> 6) & 15u; \
    st_[ix] = make_float2(A##k.x, A##k.y); }
    FE16(SC)
#undef SC
}

// final layer: wires 12,13 + ring(RI=1, r=2) + <Z> measurement, no writeback
__device__ __forceinline__ float meas_pass(float2* st_, const float4* G4, int t,
                                           unsigned fb, const float* s_hw)
{
    RING_LOAD_GATES
#define SGV(b) ((((fb >> b) & 1u) ? -1.f : 1.f) * s_hw[13 - (b)])
    const float sg0 = SGV(0),  sg1 = SGV(1),  sg2 = SGV(2),  sg3 = SGV(3),
                sg4 = SGV(4),  sg5 = SGV(5),  sg6 = SGV(6),  sg7 = SGV(7),
                sg8 = SGV(8),  sg9 = SGV(9),  sg10 = SGV(10), sg11 = SGV(11),
                sg12 = SGV(12), sg13 = SGV(13);
#undef SGV
    const float chiS = ((sg0 + sg1) + (sg2 + sg3)) + ((sg4 + sg5) + (sg6 + sg7))
                     + ((sg8 + sg9) + (sg10 + sg11)) + (sg12 + sg13);
#define SUBSUM(F) ( ((F)&1u?sg0:0.f) + ((F)&2u?sg1:0.f) + ((F)&4u?sg2:0.f) + ((F)&8u?sg3:0.f) \
                  + ((F)&16u?sg4:0.f) + ((F)&32u?sg5:0.f) + ((F)&64u?sg6:0.f) + ((F)&128u?sg7:0.f) \
                  + ((F)&256u?sg8:0.f) + ((F)&512u?sg9:0.f) + ((F)&1024u?sg10:0.f) + ((F)&2048u?sg11:0.f) \
                  + ((F)&4096u?sg12:0.f) + ((F)&8192u?sg13:0.f) )
    float acc = 0.f;
#define MEASK(k) { const float p2 = fmaf(A##k.x, A##k.x, A##k.y * A##k.y); \
    acc = fmaf(p2, chiS - 2.f * SUBSUM(RC.flow4[1][(k)]), acc); }
    FE16(MEASK)
#undef MEASK
#undef SUBSUM
    return acc;
}

__global__ __launch_bounds__(NTHREADS)
void qsim(const float* __restrict__ sb, const float* __restrict__ pr,
          const float* __restrict__ hw, const float* __restrict__ hb,
          float* __restrict__ out)
{
    __shared__ __align__(16) float2 st[STATE_SLOTS];   // 131,072 B
    __shared__ __align__(16) float4 rotc[2][NW * 4];   // gate consts (R5 format)
    __shared__ float s_hw[NW];
    __shared__ float s_red[NTHREADS / 64];
    __shared__ unsigned s_bmask;

    const int bid = blockIdx.x;
    const int t = threadIdx.x;

    // ---- setup ----
    if (t < 28) {
        int l = t / NW, w = t % NW;
        const float* pp = pr + bid * 84 + l * 42 + w * 3;
        float phi = pp[0], th = pp[1], om = pp[2];
        float s, cth;  __sincosf(0.5f * th, &s, &cth);
        float sa, ca, sd, cd;
        __sincosf(0.5f * (phi + om), &sa, &ca);
        __sincosf(0.5f * (phi - om), &sd, &cd);
        const float u00x = ca * cth, u00y = -sa * cth;
        const float u01x = -cd * s,  u01y = -sd * s;
        const float u10x = cd * s,   u10y = -sd * s;
        const float u11x = ca * cth, u11y = sa * cth;
        rotc[l][w*4+0] = make_float4(u00x, u00y, -u00y, u00y);   // {re, im, -im, +im}
        rotc[l][w*4+1] = make_float4(u01x, u01y, -u01y, u01y);
        rotc[l][w*4+2] = make_float4(u10x, u10y, -u10y, u10y);
        rotc[l][w*4+3] = make_float4(u11x, u11y, -u11y, u11y);
    }
    if (t >= 64 && t < 78) s_hw[t - 64] = hw[t - 64];
    if (t == 128) {
        const float* row = sb + (size_t)bid * (NSTATE * 2);
        unsigned m = 0;
        for (int w = 0; w < NW; ++w) m |= (row[w] < 0.0f ? 1u : 0u) << (13 - w);
        s_bmask = m;
    }
    __syncthreads();

    // ---- init: embedding state = |bm> exactly (global phase dropped) ----
    {
        const unsigned bm = s_bmask;
        const unsigned c = ((unsigned)t >> 2) & 15u;
        float2* p = st + ((unsigned)t << 4);
        const unsigned ibase = (unsigned)t << 4;
#define IW(k) p[(k) ^ c] = make_float2((ibase | (unsigned)(k)) == bm ? 1.f : 0.f, 0.f);
        FE16(IW)
#undef IW
    }
    const unsigned fb0 = fbase<0>(t);
    const unsigned fb1 = fbase<1>(t);
    __syncthreads();

    // ---- 6 layers: l = lay&1, ring r = l+1 folded into last pass ----
    float acc;
#pragma unroll 1
    for (int lay = 0; lay < 6; ++lay) {
        const float4* G4 = &rotc[lay & 1][0];
        pass_hi(st, G4, t);  __syncthreads();       // wires 0..3  (i bits 13..10)
        pass_mid(st, G4, t); __syncthreads();       // wires 4..7  (i bits 9..6)
        pass_lo2(st, G4, t); __syncthreads();       // wires 8..11 (i bits 5..2)
        if (lay == 5) {
            acc = meas_pass(st, G4, t, fb1, s_hw);  // wires 12,13 + ring2 + <Z>
            break;
        }
        if (lay & 1) ring_pass<1>(st, G4, t, fb1);  // wires 12,13 + ring r=2
        else         ring_pass<0>(st, G4, t, fb0);  // wires 12,13 + ring r=1
        __syncthreads();
    }

    for (int off = 32; off > 0; off >>= 1) acc += __shfl_down(acc, off);
    if ((t & 63) == 0) s_red[t >> 6] = acc;
    __syncthreads();
    if (t == 0) {
        float tot = 0.f;
#pragma unroll
        for (int i = 0; i < NTHREADS / 64; ++i) tot += s_red[i];
        out[bid] = tot + hb[0];
    }
}

extern "C" void kernel_launch(void* const* d_in, const int* in_sizes, int n_in,
                              void* d_out, int out_size, void* d_ws, size_t ws_size,
                              hipStream_t stream)
{
    const float* sb = (const float*)d_in[0];   // state_batch (B, 2^14, 2) f32
    const float* pr = (const float*)d_in[1];   // params (B, 84) f32
    const float* hw = (const float*)d_in[2];   // head_w (1, 14) f32
    const float* hb = (const float*)d_in[3];   // head_b (1,) f32
    float* out = (float*)d_out;                // (B,) f32
    const int B = in_sizes[1] / 84;            // 512
    qsim<<<B, NTHREADS, 0, stream>>>(sb, pr, hw, hb, out);
}

// Round 6
// 240.449 us; speedup vs baseline: 1.2321x; 1.2321x over previous
//
#include <hip/hip_runtime.h>

// 14-qubit state-vector sim, one workgroup per batch element, state in LDS.
// Wire w <-> bit (13-w). CNOT rings folded into scatter writes.
// R12: exactly R10 (1024 thr x 16 amps, 4 register-butterfly passes/layer,
//      additive-pad LDS, compile-time ds offsets — verified correct, 179 us)
//      plus ONE change: __attribute__((amdgpu_waves_per_eu(4,4))).
//      R10/R11 both allocated only 64 VGPRs (backend heuristic targets
//      8 waves/EU, ignoring that 130 KB LDS caps the CU at 16 waves = 4/EU)
//      and spilled ~60-228 MB/dispatch to scratch. Forcing the occupancy
//      target to 4 waves/EU raises the register budget to 128, which fits
//      the ~58-reg pass working set with no spill.
//      (R11's XOR swizzle reverted: its runtime per-k offsets added 16 live
//      address temps -> 4x spill, and the swizzle was wave-uniform in
//      pass_hi so bank conflicts got worse, not better.)

#define NW 14
#define NSTATE (1 << NW)                      // 16384
#define NTHREADS 1024
#define STATE_SLOTS (NSTATE + ((NSTATE >> 6) << 1))   // 16896 float2

typedef float v2f __attribute__((ext_vector_type(2)));

// ---- VOP3P packed helpers (verified R5 semantics) ----
__device__ __forceinline__ v2f pk_mul_bl(v2f a, v2f b) {   // {a.lo*b.lo, a.hi*b.lo}
    v2f d; asm("v_pk_mul_f32 %0, %1, %2 op_sel:[0,0] op_sel_hi:[1,0]"
               : "=v"(d) : "v"(a), "v"(b)); return d;
}
__device__ __forceinline__ v2f pk_fma_bl(v2f a, v2f b, v2f c) {
    v2f d; asm("v_pk_fma_f32 %0, %1, %2, %3 op_sel:[0,0,0] op_sel_hi:[1,0,1]"
               : "=v"(d) : "v"(a), "v"(b), "v"(c)); return d;
}
__device__ __forceinline__ v2f pk_fma_sw(v2f a, v2f b, v2f c) { // {a.hi*b.lo+c.lo, a.lo*b.hi+c.hi}
    v2f d; asm("v_pk_fma_f32 %0, %1, %2, %3 op_sel:[1,0,0] op_sel_hi:[0,1,1]"
               : "=v"(d) : "v"(a), "v"(b), "v"(c)); return d;
}

// ---- compile-time CNOT-ring constants ----
struct RingConsts {
    unsigned col[2][NW];      // image of basis bit under ring map (ri=0: r=1, ri=1: r=2)
    unsigned flow4[2][16];    // image of amp sub-index k (i bits 3..0)
};
constexpr RingConsts make_rc() {
    RingConsts rc{};
    for (int ri = 0; ri < 2; ++ri) {
        for (int bb = 0; bb < NW; ++bb) {
            unsigned x = 1u << bb;
            for (int w = 0; w < NW; ++w) {
                int pc = 13 - w, pt = 13 - ((w + ri + 1) % NW);
                x ^= ((x >> pc) & 1u) << pt;
            }
            rc.col[ri][bb] = x;
        }
        for (int k = 0; k < 16; ++k) {
            unsigned x = 0;
            for (int b = 0; b < 4; ++b) if ((k >> b) & 1) x ^= rc.col[ri][b];
            rc.flow4[ri][k] = x;
        }
    }
    return rc;
}
constexpr RingConsts RC = make_rc();

// base image for i = t<<4 (t bit b -> i bit b+4)
template<int RI>
__device__ __forceinline__ unsigned fbase(int t) {
    unsigned x = 0;
#pragma unroll
    for (int b = 0; b < 10; ++b) if ((t >> b) & 1) x ^= RC.col[RI][b + 4];
    return x;
}

// Gate consts per wire W (4 float4 per gate: {u.re, u.im, -u.im, +u.im})
#define GSTAGE(W) \
    const float4 g0 = G4[(W)*4+0], g1 = G4[(W)*4+1], \
                 g2 = G4[(W)*4+2], g3 = G4[(W)*4+3]; \
    const v2f U00 = (v2f){g0.x,g0.y}, V00 = (v2f){g0.z,g0.w}; \
    const v2f U01 = (v2f){g1.x,g1.y}, V01 = (v2f){g1.z,g1.w}; \
    const v2f U10 = (v2f){g2.x,g2.y}, V10 = (v2f){g2.z,g2.w}; \
    const v2f U11 = (v2f){g3.x,g3.y}, V11 = (v2f){g3.z,g3.w};

#define CBFA(X, Y) { \
    v2f n0 = pk_mul_bl(X, U00); n0 = pk_fma_sw(X, V00, n0); \
    n0 = pk_fma_bl(Y, U01, n0); n0 = pk_fma_sw(Y, V01, n0); \
    v2f n1 = pk_mul_bl(X, U10); n1 = pk_fma_sw(X, V10, n1); \
    n1 = pk_fma_bl(Y, U11, n1); n1 = pk_fma_sw(Y, V11, n1); \
    X = n0; Y = n1; }

#define FE16(M) M(0) M(1) M(2) M(3) M(4) M(5) M(6) M(7) \
                M(8) M(9) M(10) M(11) M(12) M(13) M(14) M(15)

// butterfly pair lists per k-bit (first arg has k-bit = 0)
#define Q3(M) M(A0,A8) M(A1,A9) M(A2,A10) M(A3,A11) M(A4,A12) M(A5,A13) M(A6,A14) M(A7,A15)
#define Q2(M) M(A0,A4) M(A1,A5) M(A2,A6) M(A3,A7) M(A8,A12) M(A9,A13) M(A10,A14) M(A11,A15)
#define Q1(M) M(A0,A2) M(A1,A3) M(A4,A6) M(A5,A7) M(A8,A10) M(A9,A11) M(A12,A14) M(A13,A15)
#define Q0(M) M(A0,A1) M(A2,A3) M(A4,A5) M(A6,A7) M(A8,A9) M(A10,A11) M(A12,A13) M(A14,A15)

// ---- generic in-register pass: i = base | (k<<LO); wires W0..W0+3 on k bits 3..0
template<int LO, int W0>
__device__ __forceinline__ void pass4(float2* st_, const float4* G4, int t)
{
    const int base = ((t >> LO) << (LO + 4)) | (t & ((1 << LO) - 1));
    float2* p = st_ + (base + ((base >> 6) << 1));
#define OFF(k) ((((k)) << LO) + (((((k)) << LO) >> 6) << 1))
#define LD(k) v2f A##k = *(const v2f*)(p + OFF(k));
    FE16(LD)
#undef LD
    { GSTAGE(W0+0) Q3(CBFA) }      // wire W0   <-> i bit LO+3
    { GSTAGE(W0+1) Q2(CBFA) }      // wire W0+1 <-> i bit LO+2
    { GSTAGE(W0+2) Q1(CBFA) }      // wire W0+2 <-> i bit LO+1
    { GSTAGE(W0+3) Q0(CBFA) }      // wire W0+3 <-> i bit LO
#define ST(k) *(v2f*)(p + OFF(k)) = A##k;
    FE16(ST)
#undef ST
#undef OFF
}

// ---- final pass of a layer: i = (t<<4)|k; wires 12,13 (i bits 1,0) + ring scatter
#define RING_LOAD_GATES \
    float2* p = st_ + (t * 16 + ((t >> 2) << 1)); \
    v2f A0  = *(const v2f*)(p +  0), A1  = *(const v2f*)(p +  1), \
        A2  = *(const v2f*)(p +  2), A3  = *(const v2f*)(p +  3), \
        A4  = *(const v2f*)(p +  4), A5  = *(const v2f*)(p +  5), \
        A6  = *(const v2f*)(p +  6), A7  = *(const v2f*)(p +  7), \
        A8  = *(const v2f*)(p +  8), A9  = *(const v2f*)(p +  9), \
        A10 = *(const v2f*)(p + 10), A11 = *(const v2f*)(p + 11), \
        A12 = *(const v2f*)(p + 12), A13 = *(const v2f*)(p + 13), \
        A14 = *(const v2f*)(p + 14), A15 = *(const v2f*)(p + 15); \
    { GSTAGE(12) Q1(CBFA) }        /* wire 12 <-> i bit 1 */ \
    { GSTAGE(13) Q0(CBFA) }        /* wire 13 <-> i bit 0 */

template<int RI>
__device__ __forceinline__ void ring_pass(float2* st_, const float4* G4, int t,
                                          unsigned fb)
{
    RING_LOAD_GATES
    __syncthreads();                             // all reads done before scatter
#define SC(k) { const unsigned ix = fb ^ RC.flow4[RI][(k)]; \
    st_[ix + ((ix >> 6) << 1)] = make_float2(A##k.x, A##k.y); }
    FE16(SC)
#undef SC
}

// final layer: wires 12,13 + ring(RI=1, r=2) + <Z> measurement, no writeback
__device__ __forceinline__ float meas_pass(float2* st_, const float4* G4, int t,
                                           unsigned fb, const float* s_hw)
{
    RING_LOAD_GATES
#define SGV(b) ((((fb >> b) & 1u) ? -1.f : 1.f) * s_hw[13 - (b)])
    const float sg0 = SGV(0),  sg1 = SGV(1),  sg2 = SGV(2),  sg3 = SGV(3),
                sg4 = SGV(4),  sg5 = SGV(5),  sg6 = SGV(6),  sg7 = SGV(7),
                sg8 = SGV(8),  sg9 = SGV(9),  sg10 = SGV(10), sg11 = SGV(11),
                sg12 = SGV(12), sg13 = SGV(13);
#undef SGV
    const float chiS = ((sg0 + sg1) + (sg2 + sg3)) + ((sg4 + sg5) + (sg6 + sg7))
                     + ((sg8 + sg9) + (sg10 + sg11)) + (sg12 + sg13);
#define SUBSUM(F) ( ((F)&1u?sg0:0.f) + ((F)&2u?sg1:0.f) + ((F)&4u?sg2:0.f) + ((F)&8u?sg3:0.f) \
                  + ((F)&16u?sg4:0.f) + ((F)&32u?sg5:0.f) + ((F)&64u?sg6:0.f) + ((F)&128u?sg7:0.f) \
                  + ((F)&256u?sg8:0.f) + ((F)&512u?sg9:0.f) + ((F)&1024u?sg10:0.f) + ((F)&2048u?sg11:0.f) \
                  + ((F)&4096u?sg12:0.f) + ((F)&8192u?sg13:0.f) )
    float acc = 0.f;
#define MEASK(k) { const float p2 = fmaf(A##k.x, A##k.x, A##k.y * A##k.y); \
    acc = fmaf(p2, chiS - 2.f * SUBSUM(RC.flow4[1][(k)]), acc); }
    FE16(MEASK)
#undef MEASK
#undef SUBSUM
    return acc;
}

__global__ __launch_bounds__(NTHREADS)
__attribute__((amdgpu_waves_per_eu(4, 4)))
void qsim(const float* __restrict__ sb, const float* __restrict__ pr,
          const float* __restrict__ hw, const float* __restrict__ hb,
          float* __restrict__ out)
{
    __shared__ __align__(16) float2 st[STATE_SLOTS];   // 135,168 B
    __shared__ __align__(16) float4 rotc[2][NW * 4];   // gate consts (R5 format)
    __shared__ float s_hw[NW];
    __shared__ float s_red[NTHREADS / 64];
    __shared__ unsigned s_bmask;

    const int bid = blockIdx.x;
    const int t = threadIdx.x;

    // ---- setup ----
    if (t < 28) {
        int l = t / NW, w = t % NW;
        const float* pp = pr + bid * 84 + l * 42 + w * 3;
        float phi = pp[0], th = pp[1], om = pp[2];
        float s, cth;  __sincosf(0.5f * th, &s, &cth);
        float sa, ca, sd, cd;
        __sincosf(0.5f * (phi + om), &sa, &ca);
        __sincosf(0.5f * (phi - om), &sd, &cd);
        const float u00x = ca * cth, u00y = -sa * cth;
        const float u01x = -cd * s,  u01y = -sd * s;
        const float u10x = cd * s,   u10y = -sd * s;
        const float u11x = ca * cth, u11y = sa * cth;
        rotc[l][w*4+0] = make_float4(u00x, u00y, -u00y, u00y);   // {re, im, -im, +im}
        rotc[l][w*4+1] = make_float4(u01x, u01y, -u01y, u01y);
        rotc[l][w*4+2] = make_float4(u10x, u10y, -u10y, u10y);
        rotc[l][w*4+3] = make_float4(u11x, u11y, -u11y, u11y);
    }
    if (t >= 64 && t < 78) s_hw[t - 64] = hw[t - 64];
    if (t == 128) {
        const float* row = sb + (size_t)bid * (NSTATE * 2);
        unsigned m = 0;
        for (int w = 0; w < NW; ++w) m |= (row[w] < 0.0f ? 1u : 0u) << (13 - w);
        s_bmask = m;
    }
    __syncthreads();

    // ---- init: embedding state = |bm> exactly (global phase dropped) ----
    {
        const unsigned bm = s_bmask;
        float2* p = st + (t * 16 + ((t >> 2) << 1));
        const unsigned ibase = (unsigned)t << 4;
#define IW(k) p[(k)] = make_float2((ibase | (unsigned)(k)) == bm ? 1.f : 0.f, 0.f);
        FE16(IW)
#undef IW
    }
    const unsigned fb0 = fbase<0>(t);
    const unsigned fb1 = fbase<1>(t);
    __syncthreads();

    // ---- 6 layers: l = lay&1, ring r = l+1 folded into last pass ----
    float acc;
#pragma unroll 1
    for (int lay = 0; lay < 6; ++lay) {
        const float4* G4 = &rotc[lay & 1][0];
        pass4<10, 0>(st, G4, t); __syncthreads();   // wires 0..3  (i bits 13..10)
        pass4<6, 4>(st, G4, t);  __syncthreads();   // wires 4..7  (i bits 9..6)
        pass4<2, 8>(st, G4, t);  __syncthreads();   // wires 8..11 (i bits 5..2)
        if (lay == 5) {
            acc = meas_pass(st, G4, t, fb1, s_hw);  // wires 12,13 + ring2 + <Z>
            break;
        }
        if (lay & 1) ring_pass<1>(st, G4, t, fb1);  // wires 12,13 + ring r=2
        else         ring_pass<0>(st, G4, t, fb0);  // wires 12,13 + ring r=1
        __syncthreads();
    }

    for (int off = 32; off > 0; off >>= 1) acc += __shfl_down(acc, off);
    if ((t & 63) == 0) s_red[t >> 6] = acc;
    __syncthreads();
    if (t == 0) {
        float tot = 0.f;
#pragma unroll
        for (int i = 0; i < NTHREADS / 64; ++i) tot += s_red[i];
        out[bid] = tot + hb[0];
    }
}

extern "C" void kernel_launch(void* const* d_in, const int* in_sizes, int n_in,
                              void* d_out, int out_size, void* d_ws, size_t ws_size,
                              hipStream_t stream)
{
    const float* sb = (const float*)d_in[0];   // state_batch (B, 2^14, 2) f32
    const float* pr = (const float*)d_in[1];   // params (B, 84) f32
    const float* hw = (const float*)d_in[2];   // head_w (1, 14) f32
    const float* hb = (const float*)d_in[3];   // head_b (1,) f32
    float* out = (float*)d_out;                // (B,) f32
    const int B = in_sizes[1] / 84;            // 512
    qsim<<<B, NTHREADS, 0, stream>>>(sb, pr, hw, hb, out);
}

// Round 7
// 229.654 us; speedup vs baseline: 1.2900x; 1.0470x over previous
//
#include <hip/hip_runtime.h>

// 14-qubit state-vector sim, one workgroup per batch element, state in LDS.
// Wire w <-> bit (13-w). CNOT rings folded into scatter writes.
// R13: R10 (1024 thr x 16 amps, 4 register-butterfly passes/layer, additive
//      pad, 179 us) with ONE change: gate application no longer carries the
//      redundant V = {-im,+im} const vectors. A new VOP3P helper pk_fma_im
//      uses op_sel + neg_lo to compute {c.lo - X.im*U.im, c.hi + X.re*U.im}
//      straight from U = {re, im}. Gate consts drop 16 -> 8 VGPRs per stage,
//      peak live ~46 regs, fitting the backend's hard 64-VGPR cap for
//      1024-thread workgroups (R10/R12 spilled ~60 MB/dispatch to scratch;
//      occupancy knobs failed twice to raise the cap). rotc is float2 now.

#define NW 14
#define NSTATE (1 << NW)                      // 16384
#define NTHREADS 1024
#define STATE_SLOTS (NSTATE + ((NSTATE >> 6) << 1))   // 16896 float2

typedef float v2f __attribute__((ext_vector_type(2)));

// ---- VOP3P packed helpers ----
__device__ __forceinline__ v2f pk_mul_bl(v2f a, v2f b) {   // {a.lo*b.lo, a.hi*b.lo}
    v2f d; asm("v_pk_mul_f32 %0, %1, %2 op_sel:[0,0] op_sel_hi:[1,0]"
               : "=v"(d) : "v"(a), "v"(b)); return d;
}
__device__ __forceinline__ v2f pk_fma_bl(v2f a, v2f b, v2f c) { // {a.lo*b.lo+c.lo, a.hi*b.lo+c.hi}
    v2f d; asm("v_pk_fma_f32 %0, %1, %2, %3 op_sel:[0,0,0] op_sel_hi:[1,0,1]"
               : "=v"(d) : "v"(a), "v"(b), "v"(c)); return d;
}
// {c.lo - a.hi*b.hi, c.hi + a.lo*b.hi}: complex cross-term from U={re,im} directly
__device__ __forceinline__ v2f pk_fma_im(v2f a, v2f b, v2f c) {
    v2f d; asm("v_pk_fma_f32 %0, %1, %2, %3 op_sel:[1,1,0] op_sel_hi:[0,1,1] neg_lo:[0,1,0]"
               : "=v"(d) : "v"(a), "v"(b), "v"(c)); return d;
}

// ---- compile-time CNOT-ring constants ----
struct RingConsts {
    unsigned col[2][NW];      // image of basis bit under ring map (ri=0: r=1, ri=1: r=2)
    unsigned flow4[2][16];    // image of amp sub-index k (i bits 3..0)
};
constexpr RingConsts make_rc() {
    RingConsts rc{};
    for (int ri = 0; ri < 2; ++ri) {
        for (int bb = 0; bb < NW; ++bb) {
            unsigned x = 1u << bb;
            for (int w = 0; w < NW; ++w) {
                int pc = 13 - w, pt = 13 - ((w + ri + 1) % NW);
                x ^= ((x >> pc) & 1u) << pt;
            }
            rc.col[ri][bb] = x;
        }
        for (int k = 0; k < 16; ++k) {
            unsigned x = 0;
            for (int b = 0; b < 4; ++b) if ((k >> b) & 1) x ^= rc.col[ri][b];
            rc.flow4[ri][k] = x;
        }
    }
    return rc;
}
constexpr RingConsts RC = make_rc();

// base image for i = t<<4 (t bit b -> i bit b+4)
template<int RI>
__device__ __forceinline__ unsigned fbase(int t) {
    unsigned x = 0;
#pragma unroll
    for (int b = 0; b < 10; ++b) if ((t >> b) & 1) x ^= RC.col[RI][b + 4];
    return x;
}

// Gate consts per wire W (4 float2 per gate: {u.re, u.im})
#define GSTAGE(W) \
    const float2 g0 = G4[(W)*4+0], g1 = G4[(W)*4+1], \
                 g2 = G4[(W)*4+2], g3 = G4[(W)*4+3]; \
    const v2f U00 = (v2f){g0.x,g0.y}, U01 = (v2f){g1.x,g1.y}; \
    const v2f U10 = (v2f){g2.x,g2.y}, U11 = (v2f){g3.x,g3.y};

#define CBFA(X, Y) { \
    v2f n0 = pk_mul_bl(X, U00); n0 = pk_fma_im(X, U00, n0); \
    n0 = pk_fma_bl(Y, U01, n0); n0 = pk_fma_im(Y, U01, n0); \
    v2f n1 = pk_mul_bl(X, U10); n1 = pk_fma_im(X, U10, n1); \
    n1 = pk_fma_bl(Y, U11, n1); n1 = pk_fma_im(Y, U11, n1); \
    X = n0; Y = n1; }

#define FE16(M) M(0) M(1) M(2) M(3) M(4) M(5) M(6) M(7) \
                M(8) M(9) M(10) M(11) M(12) M(13) M(14) M(15)

// butterfly pair lists per k-bit (first arg has k-bit = 0)
#define Q3(M) M(A0,A8) M(A1,A9) M(A2,A10) M(A3,A11) M(A4,A12) M(A5,A13) M(A6,A14) M(A7,A15)
#define Q2(M) M(A0,A4) M(A1,A5) M(A2,A6) M(A3,A7) M(A8,A12) M(A9,A13) M(A10,A14) M(A11,A15)
#define Q1(M) M(A0,A2) M(A1,A3) M(A4,A6) M(A5,A7) M(A8,A10) M(A9,A11) M(A12,A14) M(A13,A15)
#define Q0(M) M(A0,A1) M(A2,A3) M(A4,A5) M(A6,A7) M(A8,A9) M(A10,A11) M(A12,A13) M(A14,A15)

// ---- generic in-register pass: i = base | (k<<LO); wires W0..W0+3 on k bits 3..0
template<int LO, int W0>
__device__ __forceinline__ void pass4(float2* st_, const float2* G4, int t)
{
    const int base = ((t >> LO) << (LO + 4)) | (t & ((1 << LO) - 1));
    float2* p = st_ + (base + ((base >> 6) << 1));
#define OFF(k) ((((k)) << LO) + (((((k)) << LO) >> 6) << 1))
#define LD(k) v2f A##k = *(const v2f*)(p + OFF(k));
    FE16(LD)
#undef LD
    { GSTAGE(W0+0) Q3(CBFA) }      // wire W0   <-> i bit LO+3
    { GSTAGE(W0+1) Q2(CBFA) }      // wire W0+1 <-> i bit LO+2
    { GSTAGE(W0+2) Q1(CBFA) }      // wire W0+2 <-> i bit LO+1
    { GSTAGE(W0+3) Q0(CBFA) }      // wire W0+3 <-> i bit LO
#define ST(k) *(v2f*)(p + OFF(k)) = A##k;
    FE16(ST)
#undef ST
#undef OFF
}

// ---- final pass of a layer: i = (t<<4)|k; wires 12,13 (i bits 1,0) + ring scatter
#define RING_LOAD_GATES \
    float2* p = st_ + (t * 16 + ((t >> 2) << 1)); \
    v2f A0  = *(const v2f*)(p +  0), A1  = *(const v2f*)(p +  1), \
        A2  = *(const v2f*)(p +  2), A3  = *(const v2f*)(p +  3), \
        A4  = *(const v2f*)(p +  4), A5  = *(const v2f*)(p +  5), \
        A6  = *(const v2f*)(p +  6), A7  = *(const v2f*)(p +  7), \
        A8  = *(const v2f*)(p +  8), A9  = *(const v2f*)(p +  9), \
        A10 = *(const v2f*)(p + 10), A11 = *(const v2f*)(p + 11), \
        A12 = *(const v2f*)(p + 12), A13 = *(const v2f*)(p + 13), \
        A14 = *(const v2f*)(p + 14), A15 = *(const v2f*)(p + 15); \
    { GSTAGE(12) Q1(CBFA) }        /* wire 12 <-> i bit 1 */ \
    { GSTAGE(13) Q0(CBFA) }        /* wire 13 <-> i bit 0 */

template<int RI>
__device__ __forceinline__ void ring_pass(float2* st_, const float2* G4, int t,
                                          unsigned fb)
{
    RING_LOAD_GATES
    __syncthreads();                             // all reads done before scatter
#define SC(k) { const unsigned ix = fb ^ RC.flow4[RI][(k)]; \
    st_[ix + ((ix >> 6) << 1)] = make_float2(A##k.x, A##k.y); }
    FE16(SC)
#undef SC
}

// final layer: wires 12,13 + ring(RI=1, r=2) + <Z> measurement, no writeback
__device__ __forceinline__ float meas_pass(float2* st_, const float2* G4, int t,
                                           unsigned fb, const float* s_hw)
{
    RING_LOAD_GATES
#define SGV(b) ((((fb >> b) & 1u) ? -1.f : 1.f) * s_hw[13 - (b)])
    const float sg0 = SGV(0),  sg1 = SGV(1),  sg2 = SGV(2),  sg3 = SGV(3),
                sg4 = SGV(4),  sg5 = SGV(5),  sg6 = SGV(6),  sg7 = SGV(7),
                sg8 = SGV(8),  sg9 = SGV(9),  sg10 = SGV(10), sg11 = SGV(11),
                sg12 = SGV(12), sg13 = SGV(13);
#undef SGV
    const float chiS = ((sg0 + sg1) + (sg2 + sg3)) + ((sg4 + sg5) + (sg6 + sg7))
                     + ((sg8 + sg9) + (sg10 + sg11)) + (sg12 + sg13);
#define SUBSUM(F) ( ((F)&1u?sg0:0.f) + ((F)&2u?sg1:0.f) + ((F)&4u?sg2:0.f) + ((F)&8u?sg3:0.f) \
                  + ((F)&16u?sg4:0.f) + ((F)&32u?sg5:0.f) + ((F)&64u?sg6:0.f) + ((F)&128u?sg7:0.f) \
                  + ((F)&256u?sg8:0.f) + ((F)&512u?sg9:0.f) + ((F)&1024u?sg10:0.f) + ((F)&2048u?sg11:0.f) \
                  + ((F)&4096u?sg12:0.f) + ((F)&8192u?sg13:0.f) )
    float acc = 0.f;
#define MEASK(k) { const float p2 = fmaf(A##k.x, A##k.x, A##k.y * A##k.y); \
    acc = fmaf(p2, chiS - 2.f * SUBSUM(RC.flow4[1][(k)]), acc); }
    FE16(MEASK)
#undef MEASK
#undef SUBSUM
    return acc;
}

__global__ __launch_bounds__(NTHREADS, 4)
void qsim(const float* __restrict__ sb, const float* __restrict__ pr,
          const float* __restrict__ hw, const float* __restrict__ hb,
          float* __restrict__ out)
{
    __shared__ __align__(16) float2 st[STATE_SLOTS];   // 135,168 B
    __shared__ __align__(16) float2 rotc[2][NW * 4];   // gate consts {re, im}
    __shared__ float s_hw[NW];
    __shared__ float s_red[NTHREADS / 64];
    __shared__ unsigned s_bmask;

    const int bid = blockIdx.x;
    const int t = threadIdx.x;

    // ---- setup ----
    if (t < 28) {
        int l = t / NW, w = t % NW;
        const float* pp = pr + bid * 84 + l * 42 + w * 3;
        float phi = pp[0], th = pp[1], om = pp[2];
        float s, cth;  __sincosf(0.5f * th, &s, &cth);
        float sa, ca, sd, cd;
        __sincosf(0.5f * (phi + om), &sa, &ca);
        __sincosf(0.5f * (phi - om), &sd, &cd);
        rotc[l][w*4+0] = make_float2(ca * cth, -sa * cth);   // u00
        rotc[l][w*4+1] = make_float2(-cd * s,  -sd * s);     // u01
        rotc[l][w*4+2] = make_float2(cd * s,   -sd * s);     // u10
        rotc[l][w*4+3] = make_float2(ca * cth,  sa * cth);   // u11
    }
    if (t >= 64 && t < 78) s_hw[t - 64] = hw[t - 64];
    if (t == 128) {
        const float* row = sb + (size_t)bid * (NSTATE * 2);
        unsigned m = 0;
        for (int w = 0; w < NW; ++w) m |= (row[w] < 0.0f ? 1u : 0u) << (13 - w);
        s_bmask = m;
    }
    __syncthreads();

    // ---- init: embedding state = |bm> exactly (global phase dropped) ----
    {
        const unsigned bm = s_bmask;
        float2* p = st + (t * 16 + ((t >> 2) << 1));
        const unsigned ibase = (unsigned)t << 4;
#define IW(k) p[(k)] = make_float2((ibase | (unsigned)(k)) == bm ? 1.f : 0.f, 0.f);
        FE16(IW)
#undef IW
    }
    const unsigned fb0 = fbase<0>(t);
    const unsigned fb1 = fbase<1>(t);
    __syncthreads();

    // ---- 6 layers: l = lay&1, ring r = l+1 folded into last pass ----
    float acc;
#pragma unroll 1
    for (int lay = 0; lay < 6; ++lay) {
        const float2* G4 = &rotc[lay & 1][0];
        pass4<10, 0>(st, G4, t); __syncthreads();   // wires 0..3  (i bits 13..10)
        pass4<6, 4>(st, G4, t);  __syncthreads();   // wires 4..7  (i bits 9..6)
        pass4<2, 8>(st, G4, t);  __syncthreads();   // wires 8..11 (i bits 5..2)
        if (lay == 5) {
            acc = meas_pass(st, G4, t, fb1, s_hw);  // wires 12,13 + ring2 + <Z>
            break;
        }
        if (lay & 1) ring_pass<1>(st, G4, t, fb1);  // wires 12,13 + ring r=2
        else         ring_pass<0>(st, G4, t, fb0);  // wires 12,13 + ring r=1
        __syncthreads();
    }

    for (int off = 32; off > 0; off >>= 1) acc += __shfl_down(acc, off);
    if ((t & 63) == 0) s_red[t >> 6] = acc;
    __syncthreads();
    if (t == 0) {
        float tot = 0.f;
#pragma unroll
        for (int i = 0; i < NTHREADS / 64; ++i) tot += s_red[i];
        out[bid] = tot + hb[0];
    }
}

extern "C" void kernel_launch(void* const* d_in, const int* in_sizes, int n_in,
                              void* d_out, int out_size, void* d_ws, size_t ws_size,
                              hipStream_t stream)
{
    const float* sb = (const float*)d_in[0];   // state_batch (B, 2^14, 2) f32
    const float* pr = (const float*)d_in[1];   // params (B, 84) f32
    const float* hw = (const float*)d_in[2];   // head_w (1, 14) f32
    const float* hb = (const float*)d_in[3];   // head_b (1,) f32
    float* out = (float*)d_out;                // (B,) f32
    const int B = in_sizes[1] / 84;            // 512
    qsim<<<B, NTHREADS, 0, stream>>>(sb, pr, hw, hb, out);
}

// Round 8
// 196.588 us; speedup vs baseline: 1.5070x; 1.1682x over previous
//
#include <hip/hip_runtime.h>

// 14-qubit state-vector sim, one workgroup per batch element, state in LDS.
// Wire w <-> bit (13-w). CNOT rings folded into scatter writes.
// R14: R7 structure (512 thr x 32 amps, 3 passes/layer, folded init/ring/meas,
//      minimum ~15 state traversals — measured 130 us) + R13's verified
//      register diet: gate consts are float2 {re,im} and the cross-term uses
//      pk_fma_im (VOP3P op_sel+neg_lo), removing the redundant V={-im,+im}
//      vectors (16->8 const VGPRs per stage, half the const LDS reads).
//      Traversal model from R7/R13: wall ~ 3.6us x traversals; R7's 15 is
//      the structural minimum (5+5+4 wires/pass, init+ring+meas folded).

#define NW 14
#define NSTATE (1 << NW)                      // 16384
#define NTHREADS 512
#define STATE_SLOTS (NSTATE + ((NSTATE >> 6) << 1))   // 16896 float2

typedef float v2f __attribute__((ext_vector_type(2)));

__device__ __forceinline__ float2 cmul(float2 a, float2 b) {
    return make_float2(a.x * b.x - a.y * b.y, a.x * b.y + a.y * b.x);
}

// ---- VOP3P packed helpers (pk_fma_im verified on HW in R13, absmax 0.0) ----
__device__ __forceinline__ v2f pk_mul_bl(v2f a, v2f b) {   // {a.lo*b.lo, a.hi*b.lo}
    v2f d; asm("v_pk_mul_f32 %0, %1, %2 op_sel:[0,0] op_sel_hi:[1,0]"
               : "=v"(d) : "v"(a), "v"(b)); return d;
}
__device__ __forceinline__ v2f pk_fma_bl(v2f a, v2f b, v2f c) { // {a.lo*b.lo+c.lo, a.hi*b.lo+c.hi}
    v2f d; asm("v_pk_fma_f32 %0, %1, %2, %3 op_sel:[0,0,0] op_sel_hi:[1,0,1]"
               : "=v"(d) : "v"(a), "v"(b), "v"(c)); return d;
}
// {c.lo - a.hi*b.hi, c.hi + a.lo*b.hi}: complex cross-term from U={re,im} directly
__device__ __forceinline__ v2f pk_fma_im(v2f a, v2f b, v2f c) {
    v2f d; asm("v_pk_fma_f32 %0, %1, %2, %3 op_sel:[1,1,0] op_sel_hi:[0,1,1] neg_lo:[0,1,0]"
               : "=v"(d) : "v"(a), "v"(b), "v"(c)); return d;
}

// ---- compile-time CNOT-ring constants ----
struct RingConsts { unsigned col[2][NW]; unsigned flow[2][32]; };
constexpr RingConsts make_rc() {
    RingConsts rc{};
    for (int ri = 0; ri < 2; ++ri) {
        for (int bb = 0; bb < NW; ++bb) {
            unsigned x = 1u << bb;
            for (int w = 0; w < NW; ++w) {
                int pc = 13 - w, pt = 13 - ((w + ri + 1) % NW);
                x ^= ((x >> pc) & 1u) << pt;
            }
            rc.col[ri][bb] = x;
        }
        for (int k = 0; k < 32; ++k) {
            unsigned x = 0;
            for (int b = 0; b < 5; ++b) if ((k >> b) & 1) x ^= rc.col[ri][b];
            rc.flow[ri][k] = x;
        }
    }
    return rc;
}
constexpr RingConsts RC = make_rc();

// Gate consts per wire W (4 float2 per gate: {u.re, u.im})
#define GSTAGE(W) \
    const float2 g0 = G4[(W)*4+0], g1 = G4[(W)*4+1], \
                 g2 = G4[(W)*4+2], g3 = G4[(W)*4+3]; \
    const v2f U00 = (v2f){g0.x,g0.y}, U01 = (v2f){g1.x,g1.y}; \
    const v2f U10 = (v2f){g2.x,g2.y}, U11 = (v2f){g3.x,g3.y};

#define CBFA(X, Y) { \
    v2f n0 = pk_mul_bl(X, U00); n0 = pk_fma_im(X, U00, n0); \
    n0 = pk_fma_bl(Y, U01, n0); n0 = pk_fma_im(Y, U01, n0); \
    v2f n1 = pk_mul_bl(X, U10); n1 = pk_fma_im(X, U10, n1); \
    n1 = pk_fma_bl(Y, U11, n1); n1 = pk_fma_im(Y, U11, n1); \
    X = n0; Y = n1; }

#define FE32(M) M(0) M(1) M(2) M(3) M(4) M(5) M(6) M(7) M(8) M(9) M(10) M(11) \
    M(12) M(13) M(14) M(15) M(16) M(17) M(18) M(19) M(20) M(21) M(22) M(23) \
    M(24) M(25) M(26) M(27) M(28) M(29) M(30) M(31)

// butterfly pair lists per k-bit
#define P4(M) M(A0,A16) M(A1,A17) M(A2,A18) M(A3,A19) M(A4,A20) M(A5,A21) M(A6,A22) M(A7,A23) \
              M(A8,A24) M(A9,A25) M(A10,A26) M(A11,A27) M(A12,A28) M(A13,A29) M(A14,A30) M(A15,A31)
#define P3(M) M(A0,A8) M(A1,A9) M(A2,A10) M(A3,A11) M(A4,A12) M(A5,A13) M(A6,A14) M(A7,A15) \
              M(A16,A24) M(A17,A25) M(A18,A26) M(A19,A27) M(A20,A28) M(A21,A29) M(A22,A30) M(A23,A31)
#define P2(M) M(A0,A4) M(A1,A5) M(A2,A6) M(A3,A7) M(A8,A12) M(A9,A13) M(A10,A14) M(A11,A15) \
              M(A16,A20) M(A17,A21) M(A18,A22) M(A19,A23) M(A24,A28) M(A25,A29) M(A26,A30) M(A27,A31)
#define P1(M) M(A0,A2) M(A1,A3) M(A4,A6) M(A5,A7) M(A8,A10) M(A9,A11) M(A12,A14) M(A13,A15) \
              M(A16,A18) M(A17,A19) M(A20,A22) M(A21,A23) M(A24,A26) M(A25,A27) M(A28,A30) M(A29,A31)
#define P0(M) M(A0,A1) M(A2,A3) M(A4,A5) M(A6,A7) M(A8,A9) M(A10,A11) M(A12,A13) M(A14,A15) \
              M(A16,A17) M(A18,A19) M(A20,A21) M(A22,A23) M(A24,A25) M(A26,A27) M(A28,A29) M(A30,A31)

// 5 gates on k-bits 4..0 = wires W0..W0+4; 32 amps/thread, affine padded addrs.
template<int LO, int W0>
__device__ __forceinline__ void rot_pass5(float2* st_, const float2* G4, int t)
{
    const int base = ((t >> LO) << (LO + 5)) | (t & ((1 << LO) - 1));
    float2* pA = st_ + (base + ((base >> 6) << 1));
#define OFF(k) ((((k)) << LO) + (((((k)) << LO) >> 6) << 1))
    float2* pB = pA + OFF(16);
#define ADR(k) ((k) < 16 ? (pA + OFF(k)) : (pB + OFF((k) - 16)))
#define DECL(k) v2f A##k;
    FE32(DECL)
#undef DECL
#define LD(k) A##k = *(const v2f*)ADR(k);
    FE32(LD)
#undef LD
    { GSTAGE(W0+0) P4(CBFA) }
    { GSTAGE(W0+1) P3(CBFA) }
    { GSTAGE(W0+2) P2(CBFA) }
    { GSTAGE(W0+3) P1(CBFA) }
    { GSTAGE(W0+4) P0(CBFA) }
#define ST(k) *(v2f*)ADR(k) = A##k;
    FE32(ST)
#undef ST
#undef ADR
#undef OFF
}

// contiguous 32-amp load (b128) + gates on wires 10..13 (k-bits 3..0)
#define LOW_LOAD_GATES \
    const float4* lp = (const float4*)(st_ + (32 * t + ((t >> 1) << 1))); \
    const float4 q0 = lp[0],  q1 = lp[1],  q2 = lp[2],  q3 = lp[3], \
                 q4 = lp[4],  q5 = lp[5],  q6 = lp[6],  q7 = lp[7], \
                 q8 = lp[8],  q9 = lp[9],  q10 = lp[10], q11 = lp[11], \
                 q12 = lp[12], q13 = lp[13], q14 = lp[14], q15 = lp[15]; \
    v2f A0  = (v2f){q0.x,q0.y},  A1  = (v2f){q0.z,q0.w}, \
        A2  = (v2f){q1.x,q1.y},  A3  = (v2f){q1.z,q1.w}, \
        A4  = (v2f){q2.x,q2.y},  A5  = (v2f){q2.z,q2.w}, \
        A6  = (v2f){q3.x,q3.y},  A7  = (v2f){q3.z,q3.w}, \
        A8  = (v2f){q4.x,q4.y},  A9  = (v2f){q4.z,q4.w}, \
        A10 = (v2f){q5.x,q5.y},  A11 = (v2f){q5.z,q5.w}, \
        A12 = (v2f){q6.x,q6.y},  A13 = (v2f){q6.z,q6.w}, \
        A14 = (v2f){q7.x,q7.y},  A15 = (v2f){q7.z,q7.w}, \
        A16 = (v2f){q8.x,q8.y},  A17 = (v2f){q8.z,q8.w}, \
        A18 = (v2f){q9.x,q9.y},  A19 = (v2f){q9.z,q9.w}, \
        A20 = (v2f){q10.x,q10.y}, A21 = (v2f){q10.z,q10.w}, \
        A22 = (v2f){q11.x,q11.y}, A23 = (v2f){q11.z,q11.w}, \
        A24 = (v2f){q12.x,q12.y}, A25 = (v2f){q12.z,q12.w}, \
        A26 = (v2f){q13.x,q13.y}, A27 = (v2f){q13.z,q13.w}, \
        A28 = (v2f){q14.x,q14.y}, A29 = (v2f){q14.z,q14.w}, \
        A30 = (v2f){q15.x,q15.y}, A31 = (v2f){q15.z,q15.w}; \
    { GSTAGE(10) P3(CBFA) } \
    { GSTAGE(11) P2(CBFA) } \
    { GSTAGE(12) P1(CBFA) } \
    { GSTAGE(13) P0(CBFA) }

// wires 10..13 + ring permutation folded into scatter (full XOR + SLOT)
template<int RI>
__device__ __forceinline__ void rot_low_ring5(float2* st_, const float2* G4, int t,
                                              const unsigned* lA, const unsigned* lB)
{
    LOW_LOAD_GATES
    const unsigned fb = lA[t & 31] ^ lB[t >> 5];      // image of (t<<5), any bits
    __syncthreads();                                  // all reads done before scatter
#define SC(k) { const unsigned ix = fb ^ RC.flow[RI][(k)]; \
    st_[ix + ((ix >> 6) << 1)] = make_float2(A##k.x, A##k.y); }
    FE32(SC)
#undef SC
}

// final layer: wires 10..13 + ring(RI=1) + <Z> measurement, no writeback
__device__ __forceinline__ float rot_low_meas5(float2* st_, const float2* G4, int t,
                                               const unsigned* lA, const unsigned* lB,
                                               const float* s_hw)
{
    LOW_LOAD_GATES
    const unsigned fb = lA[t & 31] ^ lB[t >> 5];
#define SGV(b) ((((fb >> b) & 1u) ? -1.f : 1.f) * s_hw[13 - (b)])
    const float sg0 = SGV(0),  sg1 = SGV(1),  sg2 = SGV(2),  sg3 = SGV(3),
                sg4 = SGV(4),  sg5 = SGV(5),  sg6 = SGV(6),  sg7 = SGV(7),
                sg8 = SGV(8),  sg9 = SGV(9),  sg10 = SGV(10), sg11 = SGV(11),
                sg12 = SGV(12), sg13 = SGV(13);
#undef SGV
    const float chiS = ((sg0 + sg1) + (sg2 + sg3)) + ((sg4 + sg5) + (sg6 + sg7))
                     + ((sg8 + sg9) + (sg10 + sg11)) + (sg12 + sg13);
#define SUBSUM(F) ( ((F)&1u?sg0:0.f) + ((F)&2u?sg1:0.f) + ((F)&4u?sg2:0.f) + ((F)&8u?sg3:0.f) \
                  + ((F)&16u?sg4:0.f) + ((F)&32u?sg5:0.f) + ((F)&64u?sg6:0.f) + ((F)&128u?sg7:0.f) \
                  + ((F)&256u?sg8:0.f) + ((F)&512u?sg9:0.f) + ((F)&1024u?sg10:0.f) + ((F)&2048u?sg11:0.f) \
                  + ((F)&4096u?sg12:0.f) + ((F)&8192u?sg13:0.f) )
    float acc = 0.f;
#define MEASK(k) { const float p2 = fmaf(A##k.x, A##k.x, A##k.y * A##k.y); \
    acc = fmaf(p2, chiS - 2.f * SUBSUM(RC.flow[1][(k)]), acc); }
    FE32(MEASK)
#undef MEASK
#undef SUBSUM
    return acc;
}

__global__ __launch_bounds__(NTHREADS, 2)
void qsim(const float* __restrict__ sb, const float* __restrict__ pr,
          const float* __restrict__ hw, const float* __restrict__ hb,
          float* __restrict__ out)
{
    __shared__ __align__(16) float2 st[STATE_SLOTS];   // 135,168 B
    __shared__ __align__(16) float2 rotc[2][NW * 4];   // gate consts {re, im}
    __shared__ unsigned lutA[2][32], lutB[2][16];      // fb LUTs: i bits 5..9 / 10..13
    __shared__ float2 low_tab[32];                     // layer0 product over wires 9..13
    __shared__ float s_hw[NW];
    __shared__ float s_red[NTHREADS / 64];
    __shared__ unsigned s_bmask;

    const int bid = blockIdx.x;
    const int t = threadIdx.x;

    // ---- setup ----
    if (t < 28) {
        int l = t / NW, w = t % NW;
        const float* p = pr + bid * 84 + l * 42 + w * 3;
        float phi = p[0], th = p[1], om = p[2];
        float s, cth;  __sincosf(0.5f * th, &s, &cth);
        float sa, ca, sd, cd;
        __sincosf(0.5f * (phi + om), &sa, &ca);
        __sincosf(0.5f * (phi - om), &sd, &cd);
        rotc[l][w*4+0] = make_float2(ca * cth, -sa * cth);   // u00
        rotc[l][w*4+1] = make_float2(-cd * s,  -sd * s);     // u01
        rotc[l][w*4+2] = make_float2(cd * s,   -sd * s);     // u10
        rotc[l][w*4+3] = make_float2(ca * cth,  sa * cth);   // u11
    }
    if (t >= 64 && t < 128) {                   // lutA: i bits 5..9 from t bits 0..4
        int j = t - 64, ri = j >> 5, m = j & 31;
        unsigned x = 0;
        for (int b = 0; b < 5; ++b) if ((m >> b) & 1) x ^= RC.col[ri][5 + b];
        lutA[ri][m] = x;
    }
    if (t >= 128 && t < 160) {                  // lutB: i bits 10..13 from t bits 5..8
        int j = t - 128, ri = j >> 4, m = j & 15;
        unsigned x = 0;
        for (int b = 0; b < 4; ++b) if ((m >> b) & 1) x ^= RC.col[ri][10 + b];
        lutB[ri][m] = x;
    }
    if (t >= 160 && t < 174) s_hw[t - 160] = hw[t - 160];
    if (t == 192) {
        const float* row = sb + (size_t)bid * (NSTATE * 2);
        unsigned m = 0;
        for (int w = 0; w < NW; ++w) m |= (row[w] < 0.0f ? 1u : 0u) << (13 - w);
        s_bmask = m;
    }
    __syncthreads();
    if (t < 32) {                               // low_tab[k]: wires 9..13 (i bits 4..0)
        const unsigned bm = s_bmask;
        float2 v = make_float2(1.f, 0.f);
#pragma unroll
        for (int b = 0; b < 5; ++b) {
            int w = 13 - b, kb = (t >> b) & 1, cb = (bm >> b) & 1;
            float2 e = rotc[0][w*4 + kb*2 + cb];
            v = cmul(v, e);
        }
        low_tab[t] = v;
    }
    __syncthreads();

    // ---- init: layer 0 on |bm> (product state), ring r=1 folded ----
    {
        const unsigned bm = s_bmask;
        float2 ph = make_float2(1.f, 0.f);
#pragma unroll
        for (int w = 0; w < 9; ++w) {           // wires 0..8 from t bits 8..0
            int v = (t >> (8 - w)) & 1;
            int bw = (bm >> (13 - w)) & 1;
            float2 e = rotc[0][w*4 + v*2 + bw];
            ph = cmul(ph, e);
        }
        const unsigned fb = lutA[0][t & 31] ^ lutB[0][t >> 5];
#define INITK(k) { const unsigned ix = fb ^ RC.flow[0][(k)]; \
    const float2 lt = low_tab[(k)]; \
    st[ix + ((ix >> 6) << 1)] = cmul(ph, lt); }
        FE32(INITK)
#undef INITK
    }
    __syncthreads();

    // ---- reps 0..3: layers (1,0,1,0), 3 passes each, trailing ring folded ----
#pragma unroll 1
    for (int rep = 0; rep < 4; ++rep) {
        const int l = (rep & 1) ? 0 : 1;
        const float2* G4 = &rotc[l][0];
        rot_pass5<9, 0>(st, G4, t); __syncthreads();   // wires 0..4
        rot_pass5<4, 5>(st, G4, t); __syncthreads();   // wires 5..9
        if (l) rot_low_ring5<1>(st, G4, t, lutA[1], lutB[1]);
        else   rot_low_ring5<0>(st, G4, t, lutA[0], lutB[0]);
        __syncthreads();
    }
    // ---- final: layer 1, ring r=2 + measurement folded ----
    rot_pass5<9, 0>(st, &rotc[1][0], t); __syncthreads();
    rot_pass5<4, 5>(st, &rotc[1][0], t); __syncthreads();
    float acc = rot_low_meas5(st, &rotc[1][0], t, lutA[1], lutB[1], s_hw);

    for (int off = 32; off > 0; off >>= 1) acc += __shfl_down(acc, off);
    if ((t & 63) == 0) s_red[t >> 6] = acc;
    __syncthreads();
    if (t == 0) {
        float tot = 0.f;
#pragma unroll
        for (int i = 0; i < NTHREADS / 64; ++i) tot += s_red[i];
        out[bid] = tot + hb[0];
    }
}

extern "C" void kernel_launch(void* const* d_in, const int* in_sizes, int n_in,
                              void* d_out, int out_size, void* d_ws, size_t ws_size,
                              hipStream_t stream)
{
    const float* sb = (const float*)d_in[0];   // state_batch (B, 2^14, 2) f32
    const float* pr = (const float*)d_in[1];   // params (B, 84) f32
    const float* hw = (const float*)d_in[2];   // head_w (1, 14) f32
    const float* hb = (const float*)d_in[3];   // head_b (1,) f32
    float* out = (float*)d_out;                // (B,) f32
    const int B = in_sizes[1] / 84;            // 512
    qsim<<<B, NTHREADS, 0, stream>>>(sb, pr, hw, hb, out);
}

// Round 9
// 193.301 us; speedup vs baseline: 1.5326x; 1.0170x over previous
//
#include <hip/hip_runtime.h>

// 14-qubit state-vector sim, one workgroup per batch element, state in LDS.
// Wire w <-> bit (13-w). CNOT rings folded into scatter writes.
// R15: R14 (512 thr x 32 amps, 3 passes/layer, float2 consts + pk_fma_im,
//      127.9 us) with the provably-redundant barrier between pass B
//      (rot_pass5<4,5>) and pass C (rot_low_*5) removed (5 sites):
//      pass B wave w touches exactly i bits 13..11 = w; pass C reads the
//      same partition (i = 32t+k -> bits 13..11 = t bits 8..6 = w). The
//      RAW is wave-private -> s_waitcnt lgkmcnt(0) suffices (explicit asm
//      + memory clobber). A->B and the two barriers around the ring
//      scatter remain (cross-wave partitions).

#define NW 14
#define NSTATE (1 << NW)                      // 16384
#define NTHREADS 512
#define STATE_SLOTS (NSTATE + ((NSTATE >> 6) << 1))   // 16896 float2

typedef float v2f __attribute__((ext_vector_type(2)));

__device__ __forceinline__ float2 cmul(float2 a, float2 b) {
    return make_float2(a.x * b.x - a.y * b.y, a.x * b.y + a.y * b.x);
}

// wave-local LDS RAW fence: B's writes -> C's reads (same wave's chunk only)
__device__ __forceinline__ void wave_lds_fence() {
    asm volatile("s_waitcnt lgkmcnt(0)" ::: "memory");
}

// ---- VOP3P packed helpers (pk_fma_im verified on HW in R13/R14, absmax 0.0) ----
__device__ __forceinline__ v2f pk_mul_bl(v2f a, v2f b) {   // {a.lo*b.lo, a.hi*b.lo}
    v2f d; asm("v_pk_mul_f32 %0, %1, %2 op_sel:[0,0] op_sel_hi:[1,0]"
               : "=v"(d) : "v"(a), "v"(b)); return d;
}
__device__ __forceinline__ v2f pk_fma_bl(v2f a, v2f b, v2f c) { // {a.lo*b.lo+c.lo, a.hi*b.lo+c.hi}
    v2f d; asm("v_pk_fma_f32 %0, %1, %2, %3 op_sel:[0,0,0] op_sel_hi:[1,0,1]"
               : "=v"(d) : "v"(a), "v"(b), "v"(c)); return d;
}
// {c.lo - a.hi*b.hi, c.hi + a.lo*b.hi}: complex cross-term from U={re,im} directly
__device__ __forceinline__ v2f pk_fma_im(v2f a, v2f b, v2f c) {
    v2f d; asm("v_pk_fma_f32 %0, %1, %2, %3 op_sel:[1,1,0] op_sel_hi:[0,1,1] neg_lo:[0,1,0]"
               : "=v"(d) : "v"(a), "v"(b), "v"(c)); return d;
}

// ---- compile-time CNOT-ring constants ----
struct RingConsts { unsigned col[2][NW]; unsigned flow[2][32]; };
constexpr RingConsts make_rc() {
    RingConsts rc{};
    for (int ri = 0; ri < 2; ++ri) {
        for (int bb = 0; bb < NW; ++bb) {
            unsigned x = 1u << bb;
            for (int w = 0; w < NW; ++w) {
                int pc = 13 - w, pt = 13 - ((w + ri + 1) % NW);
                x ^= ((x >> pc) & 1u) << pt;
            }
            rc.col[ri][bb] = x;
        }
        for (int k = 0; k < 32; ++k) {
            unsigned x = 0;
            for (int b = 0; b < 5; ++b) if ((k >> b) & 1) x ^= rc.col[ri][b];
            rc.flow[ri][k] = x;
        }
    }
    return rc;
}
constexpr RingConsts RC = make_rc();

// Gate consts per wire W (4 float2 per gate: {u.re, u.im})
#define GSTAGE(W) \
    const float2 g0 = G4[(W)*4+0], g1 = G4[(W)*4+1], \
                 g2 = G4[(W)*4+2], g3 = G4[(W)*4+3]; \
    const v2f U00 = (v2f){g0.x,g0.y}, U01 = (v2f){g1.x,g1.y}; \
    const v2f U10 = (v2f){g2.x,g2.y}, U11 = (v2f){g3.x,g3.y};

#define CBFA(X, Y) { \
    v2f n0 = pk_mul_bl(X, U00); n0 = pk_fma_im(X, U00, n0); \
    n0 = pk_fma_bl(Y, U01, n0); n0 = pk_fma_im(Y, U01, n0); \
    v2f n1 = pk_mul_bl(X, U10); n1 = pk_fma_im(X, U10, n1); \
    n1 = pk_fma_bl(Y, U11, n1); n1 = pk_fma_im(Y, U11, n1); \
    X = n0; Y = n1; }

#define FE32(M) M(0) M(1) M(2) M(3) M(4) M(5) M(6) M(7) M(8) M(9) M(10) M(11) \
    M(12) M(13) M(14) M(15) M(16) M(17) M(18) M(19) M(20) M(21) M(22) M(23) \
    M(24) M(25) M(26) M(27) M(28) M(29) M(30) M(31)

// butterfly pair lists per k-bit
#define P4(M) M(A0,A16) M(A1,A17) M(A2,A18) M(A3,A19) M(A4,A20) M(A5,A21) M(A6,A22) M(A7,A23) \
              M(A8,A24) M(A9,A25) M(A10,A26) M(A11,A27) M(A12,A28) M(A13,A29) M(A14,A30) M(A15,A31)
#define P3(M) M(A0,A8) M(A1,A9) M(A2,A10) M(A3,A11) M(A4,A12) M(A5,A13) M(A6,A14) M(A7,A15) \
              M(A16,A24) M(A17,A25) M(A18,A26) M(A19,A27) M(A20,A28) M(A21,A29) M(A22,A30) M(A23,A31)
#define P2(M) M(A0,A4) M(A1,A5) M(A2,A6) M(A3,A7) M(A8,A12) M(A9,A13) M(A10,A14) M(A11,A15) \
              M(A16,A20) M(A17,A21) M(A18,A22) M(A19,A23) M(A24,A28) M(A25,A29) M(A26,A30) M(A27,A31)
#define P1(M) M(A0,A2) M(A1,A3) M(A4,A6) M(A5,A7) M(A8,A10) M(A9,A11) M(A12,A14) M(A13,A15) \
              M(A16,A18) M(A17,A19) M(A20,A22) M(A21,A23) M(A24,A26) M(A25,A27) M(A28,A30) M(A29,A31)
#define P0(M) M(A0,A1) M(A2,A3) M(A4,A5) M(A6,A7) M(A8,A9) M(A10,A11) M(A12,A13) M(A14,A15) \
              M(A16,A17) M(A18,A19) M(A20,A21) M(A22,A23) M(A24,A25) M(A26,A27) M(A28,A29) M(A30,A31)

// 5 gates on k-bits 4..0 = wires W0..W0+4; 32 amps/thread, affine padded addrs.
template<int LO, int W0>
__device__ __forceinline__ void rot_pass5(float2* st_, const float2* G4, int t)
{
    const int base = ((t >> LO) << (LO + 5)) | (t & ((1 << LO) - 1));
    float2* pA = st_ + (base + ((base >> 6) << 1));
#define OFF(k) ((((k)) << LO) + (((((k)) << LO) >> 6) << 1))
    float2* pB = pA + OFF(16);
#define ADR(k) ((k) < 16 ? (pA + OFF(k)) : (pB + OFF((k) - 16)))
#define DECL(k) v2f A##k;
    FE32(DECL)
#undef DECL
#define LD(k) A##k = *(const v2f*)ADR(k);
    FE32(LD)
#undef LD
    { GSTAGE(W0+0) P4(CBFA) }
    { GSTAGE(W0+1) P3(CBFA) }
    { GSTAGE(W0+2) P2(CBFA) }
    { GSTAGE(W0+3) P1(CBFA) }
    { GSTAGE(W0+4) P0(CBFA) }
#define ST(k) *(v2f*)ADR(k) = A##k;
    FE32(ST)
#undef ST
#undef ADR
#undef OFF
}

// contiguous 32-amp load (b128) + gates on wires 10..13 (k-bits 3..0)
#define LOW_LOAD_GATES \
    const float4* lp = (const float4*)(st_ + (32 * t + ((t >> 1) << 1))); \
    const float4 q0 = lp[0],  q1 = lp[1],  q2 = lp[2],  q3 = lp[3], \
                 q4 = lp[4],  q5 = lp[5],  q6 = lp[6],  q7 = lp[7], \
                 q8 = lp[8],  q9 = lp[9],  q10 = lp[10], q11 = lp[11], \
                 q12 = lp[12], q13 = lp[13], q14 = lp[14], q15 = lp[15]; \
    v2f A0  = (v2f){q0.x,q0.y},  A1  = (v2f){q0.z,q0.w}, \
        A2  = (v2f){q1.x,q1.y},  A3  = (v2f){q1.z,q1.w}, \
        A4  = (v2f){q2.x,q2.y},  A5  = (v2f){q2.z,q2.w}, \
        A6  = (v2f){q3.x,q3.y},  A7  = (v2f){q3.z,q3.w}, \
        A8  = (v2f){q4.x,q4.y},  A9  = (v2f){q4.z,q4.w}, \
        A10 = (v2f){q5.x,q5.y},  A11 = (v2f){q5.z,q5.w}, \
        A12 = (v2f){q6.x,q6.y},  A13 = (v2f){q6.z,q6.w}, \
        A14 = (v2f){q7.x,q7.y},  A15 = (v2f){q7.z,q7.w}, \
        A16 = (v2f){q8.x,q8.y},  A17 = (v2f){q8.z,q8.w}, \
        A18 = (v2f){q9.x,q9.y},  A19 = (v2f){q9.z,q9.w}, \
        A20 = (v2f){q10.x,q10.y}, A21 = (v2f){q10.z,q10.w}, \
        A22 = (v2f){q11.x,q11.y}, A23 = (v2f){q11.z,q11.w}, \
        A24 = (v2f){q12.x,q12.y}, A25 = (v2f){q12.z,q12.w}, \
        A26 = (v2f){q13.x,q13.y}, A27 = (v2f){q13.z,q13.w}, \
        A28 = (v2f){q14.x,q14.y}, A29 = (v2f){q14.z,q14.w}, \
        A30 = (v2f){q15.x,q15.y}, A31 = (v2f){q15.z,q15.w}; \
    { GSTAGE(10) P3(CBFA) } \
    { GSTAGE(11) P2(CBFA) } \
    { GSTAGE(12) P1(CBFA) } \
    { GSTAGE(13) P0(CBFA) }

// wires 10..13 + ring permutation folded into scatter (full XOR + SLOT)
template<int RI>
__device__ __forceinline__ void rot_low_ring5(float2* st_, const float2* G4, int t,
                                              const unsigned* lA, const unsigned* lB)
{
    LOW_LOAD_GATES
    const unsigned fb = lA[t & 31] ^ lB[t >> 5];      // image of (t<<5), any bits
    __syncthreads();                                  // all reads done before scatter
#define SC(k) { const unsigned ix = fb ^ RC.flow[RI][(k)]; \
    st_[ix + ((ix >> 6) << 1)] = make_float2(A##k.x, A##k.y); }
    FE32(SC)
#undef SC
}

// final layer: wires 10..13 + ring(RI=1) + <Z> measurement, no writeback
__device__ __forceinline__ float rot_low_meas5(float2* st_, const float2* G4, int t,
                                               const unsigned* lA, const unsigned* lB,
                                               const float* s_hw)
{
    LOW_LOAD_GATES
    const unsigned fb = lA[t & 31] ^ lB[t >> 5];
#define SGV(b) ((((fb >> b) & 1u) ? -1.f : 1.f) * s_hw[13 - (b)])
    const float sg0 = SGV(0),  sg1 = SGV(1),  sg2 = SGV(2),  sg3 = SGV(3),
                sg4 = SGV(4),  sg5 = SGV(5),  sg6 = SGV(6),  sg7 = SGV(7),
                sg8 = SGV(8),  sg9 = SGV(9),  sg10 = SGV(10), sg11 = SGV(11),
                sg12 = SGV(12), sg13 = SGV(13);
#undef SGV
    const float chiS = ((sg0 + sg1) + (sg2 + sg3)) + ((sg4 + sg5) + (sg6 + sg7))
                     + ((sg8 + sg9) + (sg10 + sg11)) + (sg12 + sg13);
#define SUBSUM(F) ( ((F)&1u?sg0:0.f) + ((F)&2u?sg1:0.f) + ((F)&4u?sg2:0.f) + ((F)&8u?sg3:0.f) \
                  + ((F)&16u?sg4:0.f) + ((F)&32u?sg5:0.f) + ((F)&64u?sg6:0.f) + ((F)&128u?sg7:0.f) \
                  + ((F)&256u?sg8:0.f) + ((F)&512u?sg9:0.f) + ((F)&1024u?sg10:0.f) + ((F)&2048u?sg11:0.f) \
                  + ((F)&4096u?sg12:0.f) + ((F)&8192u?sg13:0.f) )
    float acc = 0.f;
#define MEASK(k) { const float p2 = fmaf(A##k.x, A##k.x, A##k.y * A##k.y); \
    acc = fmaf(p2, chiS - 2.f * SUBSUM(RC.flow[1][(k)]), acc); }
    FE32(MEASK)
#undef MEASK
#undef SUBSUM
    return acc;
}

__global__ __launch_bounds__(NTHREADS, 2)
void qsim(const float* __restrict__ sb, const float* __restrict__ pr,
          const float* __restrict__ hw, const float* __restrict__ hb,
          float* __restrict__ out)
{
    __shared__ __align__(16) float2 st[STATE_SLOTS];   // 135,168 B
    __shared__ __align__(16) float2 rotc[2][NW * 4];   // gate consts {re, im}
    __shared__ unsigned lutA[2][32], lutB[2][16];      // fb LUTs: i bits 5..9 / 10..13
    __shared__ float2 low_tab[32];                     // layer0 product over wires 9..13
    __shared__ float s_hw[NW];
    __shared__ float s_red[NTHREADS / 64];
    __shared__ unsigned s_bmask;

    const int bid = blockIdx.x;
    const int t = threadIdx.x;

    // ---- setup ----
    if (t < 28) {
        int l = t / NW, w = t % NW;
        const float* p = pr + bid * 84 + l * 42 + w * 3;
        float phi = p[0], th = p[1], om = p[2];
        float s, cth;  __sincosf(0.5f * th, &s, &cth);
        float sa, ca, sd, cd;
        __sincosf(0.5f * (phi + om), &sa, &ca);
        __sincosf(0.5f * (phi - om), &sd, &cd);
        rotc[l][w*4+0] = make_float2(ca * cth, -sa * cth);   // u00
        rotc[l][w*4+1] = make_float2(-cd * s,  -sd * s);     // u01
        rotc[l][w*4+2] = make_float2(cd * s,   -sd * s);     // u10
        rotc[l][w*4+3] = make_float2(ca * cth,  sa * cth);   // u11
    }
    if (t >= 64 && t < 128) {                   // lutA: i bits 5..9 from t bits 0..4
        int j = t - 64, ri = j >> 5, m = j & 31;
        unsigned x = 0;
        for (int b = 0; b < 5; ++b) if ((m >> b) & 1) x ^= RC.col[ri][5 + b];
        lutA[ri][m] = x;
    }
    if (t >= 128 && t < 160) {                  // lutB: i bits 10..13 from t bits 5..8
        int j = t - 128, ri = j >> 4, m = j & 15;
        unsigned x = 0;
        for (int b = 0; b < 4; ++b) if ((m >> b) & 1) x ^= RC.col[ri][10 + b];
        lutB[ri][m] = x;
    }
    if (t >= 160 && t < 174) s_hw[t - 160] = hw[t - 160];
    if (t == 192) {
        const float* row = sb + (size_t)bid * (NSTATE * 2);
        unsigned m = 0;
        for (int w = 0; w < NW; ++w) m |= (row[w] < 0.0f ? 1u : 0u) << (13 - w);
        s_bmask = m;
    }
    __syncthreads();
    if (t < 32) {                               // low_tab[k]: wires 9..13 (i bits 4..0)
        const unsigned bm = s_bmask;
        float2 v = make_float2(1.f, 0.f);
#pragma unroll
        for (int b = 0; b < 5; ++b) {
            int w = 13 - b, kb = (t >> b) & 1, cb = (bm >> b) & 1;
            float2 e = rotc[0][w*4 + kb*2 + cb];
            v = cmul(v, e);
        }
        low_tab[t] = v;
    }
    __syncthreads();

    // ---- init: layer 0 on |bm> (product state), ring r=1 folded ----
    {
        const unsigned bm = s_bmask;
        float2 ph = make_float2(1.f, 0.f);
#pragma unroll
        for (int w = 0; w < 9; ++w) {           // wires 0..8 from t bits 8..0
            int v = (t >> (8 - w)) & 1;
            int bw = (bm >> (13 - w)) & 1;
            float2 e = rotc[0][w*4 + v*2 + bw];
            ph = cmul(ph, e);
        }
        const unsigned fb = lutA[0][t & 31] ^ lutB[0][t >> 5];
#define INITK(k) { const unsigned ix = fb ^ RC.flow[0][(k)]; \
    const float2 lt = low_tab[(k)]; \
    st[ix + ((ix >> 6) << 1)] = cmul(ph, lt); }
        FE32(INITK)
#undef INITK
    }
    __syncthreads();

    // ---- reps 0..3: layers (1,0,1,0), 3 passes each, trailing ring folded ----
    // B -> C barrier dropped: both partition the state by i bits 13..11 = wave id
    // (B: t bits 8..6 -> i bits 13..11; C: i = 32t+k -> same). Wave-private RAW
    // needs only lgkmcnt(0) (wave_lds_fence), not s_barrier.
#pragma unroll 1
    for (int rep = 0; rep < 4; ++rep) {
        const int l = (rep & 1) ? 0 : 1;
        const float2* G4 = &rotc[l][0];
        rot_pass5<9, 0>(st, G4, t); __syncthreads();   // wires 0..4
        rot_pass5<4, 5>(st, G4, t); wave_lds_fence();  // wires 5..9 (wave-local vs C)
        if (l) rot_low_ring5<1>(st, G4, t, lutA[1], lutB[1]);
        else   rot_low_ring5<0>(st, G4, t, lutA[0], lutB[0]);
        __syncthreads();
    }
    // ---- final: layer 1, ring r=2 + measurement folded ----
    rot_pass5<9, 0>(st, &rotc[1][0], t); __syncthreads();
    rot_pass5<4, 5>(st, &rotc[1][0], t); wave_lds_fence();
    float acc = rot_low_meas5(st, &rotc[1][0], t, lutA[1], lutB[1], s_hw);

    for (int off = 32; off > 0; off >>= 1) acc += __shfl_down(acc, off);
    if ((t & 63) == 0) s_red[t >> 6] = acc;
    __syncthreads();
    if (t == 0) {
        float tot = 0.f;
#pragma unroll
        for (int i = 0; i < NTHREADS / 64; ++i) tot += s_red[i];
        out[bid] = tot + hb[0];
    }
}

extern "C" void kernel_launch(void* const* d_in, const int* in_sizes, int n_in,
                              void* d_out, int out_size, void* d_ws, size_t ws_size,
                              hipStream_t stream)
{
    const float* sb = (const float*)d_in[0];   // state_batch (B, 2^14, 2) f32
    const float* pr = (const float*)d_in[1];   // params (B, 84) f32
    const float* hw = (const float*)d_in[2];   // head_w (1, 14) f32
    const float* hb = (const float*)d_in[3];   // head_b (1,) f32
    float* out = (float*)d_out;                // (B,) f32
    const int B = in_sizes[1] / 84;            // 512
    qsim<<<B, NTHREADS, 0, stream>>>(sb, pr, hw, hb, out);
}